// Round 2
// baseline (401.691 us; speedup 1.0000x reference)
//
#include <hip/hip_runtime.h>
#include <hip/hip_bf16.h>
#include <stdint.h>

#define BB 4
#define NN 512
#define MM 32
#define DD 64
#define HH 64

typedef _Float16 f16;
typedef _Float16 half8 __attribute__((ext_vector_type(8)));
typedef _Float16 half4 __attribute__((ext_vector_type(4)));
typedef float fx4 __attribute__((ext_vector_type(4)));

// ---------------- P1: s1t[b][h][n] = (s@Ws1+bs1)[b][n][h], s2t likewise ----------
// grid = B*N/2 blocks x 256 thr; waves uniform in (row, which)
__global__ void k_proj_s(const float* __restrict__ s,
                         const float* __restrict__ Ws1, const float* __restrict__ bs1,
                         const float* __restrict__ Ws2, const float* __restrict__ bs2,
                         float* __restrict__ s1t, float* __restrict__ s2t) {
    int t = threadIdx.x;
    int row = blockIdx.x * 2 + (t >> 7);     // flat b*N+n
    int which = (t >> 6) & 1;
    int h = t & 63;
    const float* W = which ? Ws2 : Ws1;
    const float* bias = which ? bs2 : bs1;
    const float* srow = s + row * DD;
    float acc = bias[h];
#pragma unroll
    for (int d = 0; d < DD; ++d) acc += srow[d] * W[d * HH + h];
    int b = row >> 9, n = row & 511;
    (which ? s2t : s1t)[((size_t)b * HH + h) * NN + n] = acc;  // transposed [b][h][n]
}

// ---------------- P2: V1t[b][h][n][m] = f16( sum_d v1[b,n,m,d]*Wv1[d,h] ), same V2t
// grid = B*N blocks x 256 thr (half threads per tensor)
__global__ void k_proj_v(const float* __restrict__ v1, const float* __restrict__ v0,
                         const float* __restrict__ Wv1, const float* __restrict__ Wv2,
                         f16* __restrict__ V1t, f16* __restrict__ V2t) {
    __shared__ float vA[MM * 68];    // stride 68: keeps float4 alignment, spreads banks
    __shared__ float vB[MM * 68];
    __shared__ float w1[DD * HH];
    __shared__ float w2[DD * HH];
    int t = threadIdx.x;             // 256
    int bn = blockIdx.x;             // b*N + n
    const float* v1p = v1 + (size_t)bn * (MM * DD);
    const float* v0p = v0 + (size_t)bn * (MM * DD);
    {
        int m = t >> 3, d = (t & 7) * 8;
        *(fx4*)&vA[m * 68 + d]     = *(const fx4*)&v1p[m * 64 + d];
        *(fx4*)&vA[m * 68 + d + 4] = *(const fx4*)&v1p[m * 64 + d + 4];
        *(fx4*)&vB[m * 68 + d]     = *(const fx4*)&v0p[m * 64 + d];
        *(fx4*)&vB[m * 68 + d + 4] = *(const fx4*)&v0p[m * 64 + d + 4];
    }
#pragma unroll
    for (int k = 0; k < 4; ++k) {
        int idx = k * 1024 + t * 4;
        *(fx4*)&w1[idx] = *(const fx4*)&Wv1[idx];
        *(fx4*)&w2[idx] = *(const fx4*)&Wv2[idx];
    }
    __syncthreads();
    int half_ = t >> 7;              // 0: V1 from v1, 1: V2 from v0
    int tid2 = t & 127;
    int mg = tid2 >> 4;              // m base = mg*4
    int hg = tid2 & 15;              // h base = hg*4
    const float* vS = half_ ? vB : vA;
    const float* wS = half_ ? w2 : w1;
    float acc[4][4] = {};
    for (int d = 0; d < DD; ++d) {
        fx4 w4 = *(const fx4*)&wS[d * HH + hg * 4];
#pragma unroll
        for (int mi = 0; mi < 4; ++mi) {
            float vv = vS[(mg * 4 + mi) * 68 + d];
#pragma unroll
            for (int hi = 0; hi < 4; ++hi) acc[mi][hi] += vv * w4[hi];
        }
    }
    int b = bn >> 9, n = bn & 511;
    f16* outp = half_ ? V2t : V1t;
#pragma unroll
    for (int hi = 0; hi < 4; ++hi) {
        int h = hg * 4 + hi;
        half4 hv;
#pragma unroll
        for (int mi = 0; mi < 4; ++mi) hv[mi] = (f16)acc[mi][hi];
        *(half4*)(outp + (((size_t)(b * HH + h) * NN + n) * MM + mg * 4)) = hv;
    }
}

// ---------------- P3: transpose MLP weights to f16 [h_out][h_in] ----------------
__global__ void k_prep_w(const float* __restrict__ Wm1, const float* __restrict__ Wm2,
                         f16* __restrict__ Wm1T, f16* __restrict__ Wm2T) {
    int t = threadIdx.x;
#pragma unroll
    for (int k = 0; k < 16; ++k) {
        int idx = k * 256 + t;       // idx = hp*64 + h
        int hp = idx >> 6, h = idx & 63;
        Wm1T[idx] = (f16)Wm1[h * 64 + hp];
        Wm2T[idx] = (f16)Wm2[h * 64 + hp];
    }
}

// ---------------- main: pair (MFMA) -> scale(per-h!) -> MLP (MFMA, swapped) ------
#define TI 32
#define TJ 16

__global__ __launch_bounds__(512, 2)
void k_main(const f16* __restrict__ V1t, const f16* __restrict__ V2t,
            const float* __restrict__ s1t, const float* __restrict__ s2t,
            const f16* __restrict__ Wm1T, const float* __restrict__ bm1,
            const f16* __restrict__ Wm2T, const float* __restrict__ bm2,
            float* __restrict__ out) {
    // x / hid buffer: 512 rows (p = i_local*16 + j_local) x 64 h (f16), row = 128B,
    // XOR-swizzled with ((p&7)<<4) to spread the stride-128B bank pattern.
    __shared__ __attribute__((aligned(128))) unsigned char xbuf[TI * TJ * HH * 2]; // 64 KB
    const int t = threadIdx.x;
    const int lane = t & 63;
    const int w = t >> 6;            // wave 0..7, owns h in [8w,8w+8) then p in [64w,64w+64)
    const int l15 = lane & 15;
    const int l4 = lane >> 4;        // 0..3
    const int bx = blockIdx.x;
    const int b = bx >> 9;
    const int rem = bx & 511;
    const int it = rem >> 5;         // 0..15
    const int jt = rem & 31;         // 0..31
    const int i0 = it * TI, j0 = jt * TJ;

    const f16* Abase = V1t + ((size_t)b * HH * NN + i0) * MM;
    const f16* Bbase = V2t + ((size_t)b * HH * NN + j0) * MM;

    // ---- phase 1: pair[i][j][h] for this wave's 8 h values
    // A-frag: row i = l15 (+16), k=m=(l4)*8+e -> 16B contiguous in V1t[b][h][i][m]
    fx4 pacc[8][2];
#pragma unroll
    for (int hh = 0; hh < 8; ++hh) {
        const int h = w * 8 + hh;
        const f16* Ah = Abase + (size_t)h * (NN * MM);
        const f16* Bh = Bbase + (size_t)h * (NN * MM);
        half8 a0 = *(const half8*)(Ah + l15 * MM + l4 * 8);
        half8 a1 = *(const half8*)(Ah + (16 + l15) * MM + l4 * 8);
        half8 b0 = *(const half8*)(Bh + l15 * MM + l4 * 8);
        fx4 z = {0.f, 0.f, 0.f, 0.f};
        pacc[hh][0] = __builtin_amdgcn_mfma_f32_16x16x32_f16(a0, b0, z, 0, 0, 0);
        pacc[hh][1] = __builtin_amdgcn_mfma_f32_16x16x32_f16(a1, b0, z, 0, 0, 0);
    }

    // ---- phase 1.5: x[i][j][h] = s1[b][i][h] * s2[b][j][h] * pair  (PER-H scale)
#pragma unroll
    for (int hh = 0; hh < 8; ++hh) {
        const int h = w * 8 + hh;
        const float* s1p = s1t + ((size_t)b * HH + h) * NN;
        const float* s2p = s2t + ((size_t)b * HH + h) * NN;
        const float s2v = s2p[j0 + l15];                   // j = j0 + col(l15)
        fx4 sa = *(const fx4*)&s1p[i0 + l4 * 4];           // i rows, ti=0
        fx4 sb = *(const fx4*)&s1p[i0 + 16 + l4 * 4];      // i rows, ti=1
#pragma unroll
        for (int r = 0; r < 4; ++r) {
            pacc[hh][0][r] *= sa[r] * s2v;
            pacc[hh][1][r] *= sb[r] * s2v;
        }
    }
    // pack 8 h per lane -> one b128 LDS write per (ti, r)
#pragma unroll
    for (int ti = 0; ti < 2; ++ti) {
#pragma unroll
        for (int r = 0; r < 4; ++r) {
            const int p = (ti * 16 + l4 * 4 + r) * TJ + l15;
            half8 xv;
#pragma unroll
            for (int hh = 0; hh < 8; ++hh) xv[hh] = (f16)pacc[hh][ti][r];
            *(half8*)(xbuf + p * 128 + ((w * 16) ^ ((p & 7) << 4))) = xv;
        }
    }
    __syncthreads();  // only barrier: x rows written by all waves, read per-wave

    // ---- phase 2: MLP1 swapped: D[h'][p] = sum_h Wm1T[h'][h] * x[p][h]
    half8 wf[4][2];
#pragma unroll
    for (int ht = 0; ht < 4; ++ht)
#pragma unroll
        for (int ks = 0; ks < 2; ++ks)
            wf[ht][ks] = *(const half8*)(Wm1T + (ht * 16 + l15) * 64 + ks * 32 + l4 * 8);

    fx4 hacc[4][4];  // [pt][ht]
#pragma unroll
    for (int pt = 0; pt < 4; ++pt) {
        const int p = w * 64 + pt * 16 + l15;
        const int rowb = p * 128, sw = (p & 7) << 4;
        half8 x0 = *(const half8*)(xbuf + rowb + ((0  + l4 * 16) ^ sw));
        half8 x1 = *(const half8*)(xbuf + rowb + ((64 + l4 * 16) ^ sw));
#pragma unroll
        for (int ht = 0; ht < 4; ++ht) {
            fx4 z = {0.f, 0.f, 0.f, 0.f};
            fx4 a0 = __builtin_amdgcn_mfma_f32_16x16x32_f16(wf[ht][0], x0, z, 0, 0, 0);
            hacc[pt][ht] = __builtin_amdgcn_mfma_f32_16x16x32_f16(wf[ht][1], x1, a0, 0, 0, 0);
        }
    }
    // bias + relu + write hid back over xbuf (rows are wave-private: no barrier)
#pragma unroll
    for (int ht = 0; ht < 4; ++ht) {
        fx4 b1 = *(const fx4*)&bm1[ht * 16 + l4 * 4];
#pragma unroll
        for (int pt = 0; pt < 4; ++pt) {
            const int p = w * 64 + pt * 16 + l15;
            half4 hv;
#pragma unroll
            for (int r = 0; r < 4; ++r) {
                float vv = hacc[pt][ht][r] + b1[r];
                hv[r] = (f16)(vv > 0.f ? vv : 0.f);
            }
            *(half4*)(xbuf + p * 128 + ((ht * 32 + l4 * 8) ^ ((p & 7) << 4))) = hv;
        }
    }

    // ---- phase 3: MLP2 swapped: out[h''][p] = sum_h' Wm2T[h''][h'] * hid[p][h']
#pragma unroll
    for (int ht = 0; ht < 4; ++ht)
#pragma unroll
        for (int ks = 0; ks < 2; ++ks)
            wf[ht][ks] = *(const half8*)(Wm2T + (ht * 16 + l15) * 64 + ks * 32 + l4 * 8);

    fx4 oacc[4][4];
#pragma unroll
    for (int pt = 0; pt < 4; ++pt) {
        const int p = w * 64 + pt * 16 + l15;
        const int rowb = p * 128, sw = (p & 7) << 4;
        half8 h0 = *(const half8*)(xbuf + rowb + ((0  + l4 * 16) ^ sw));
        half8 h1 = *(const half8*)(xbuf + rowb + ((64 + l4 * 16) ^ sw));
#pragma unroll
        for (int ht = 0; ht < 4; ++ht) {
            fx4 z = {0.f, 0.f, 0.f, 0.f};
            fx4 a0 = __builtin_amdgcn_mfma_f32_16x16x32_f16(wf[ht][0], h0, z, 0, 0, 0);
            oacc[pt][ht] = __builtin_amdgcn_mfma_f32_16x16x32_f16(wf[ht][1], h1, a0, 0, 0, 0);
        }
    }
    // ---- epilogue: + bm2, store float4; lanes {l,l+16,l+32,l+48} tile 64B lines
#pragma unroll
    for (int pt = 0; pt < 4; ++pt) {
        const int p = w * 64 + pt * 16 + l15;
        const int i = i0 + (p >> 4), j = j0 + (p & 15);
        float* orow = out + ((size_t)(b * NN + i) * NN + j) * HH;
#pragma unroll
        for (int ht = 0; ht < 4; ++ht) {
            fx4 b2 = *(const fx4*)&bm2[ht * 16 + l4 * 4];
            fx4 res;
#pragma unroll
            for (int r = 0; r < 4; ++r) res[r] = oacc[pt][ht][r] + b2[r];
            *(fx4*)(orow + ht * 16 + l4 * 4) = res;
        }
    }
}

extern "C" void kernel_launch(void* const* d_in, const int* in_sizes, int n_in,
                              void* d_out, int out_size, void* d_ws, size_t ws_size,
                              hipStream_t stream) {
    (void)in_sizes; (void)n_in; (void)out_size; (void)ws_size;
    const float* s   = (const float*)d_in[0];
    const float* v1  = (const float*)d_in[1];
    const float* v0  = (const float*)d_in[2];
    const float* Ws1 = (const float*)d_in[3];
    const float* bs1 = (const float*)d_in[4];
    const float* Ws2 = (const float*)d_in[5];
    const float* bs2 = (const float*)d_in[6];
    const float* Wv1 = (const float*)d_in[7];
    const float* Wv2 = (const float*)d_in[8];
    const float* Wm1 = (const float*)d_in[9];
    const float* bm1 = (const float*)d_in[10];
    const float* Wm2 = (const float*)d_in[11];
    const float* bm2 = (const float*)d_in[12];
    float* out = (float*)d_out;

    char* ws = (char*)d_ws;
    f16*   V1t  = (f16*)(ws);                                        // 8 MB
    f16*   V2t  = (f16*)(ws + (size_t)8  * 1024 * 1024);             // 8 MB
    float* s1t  = (float*)(ws + (size_t)16 * 1024 * 1024);           // 512 KB [b][h][n]
    float* s2t  = (float*)(ws + (size_t)16 * 1024 * 1024 + 512*1024);// 512 KB [b][h][n]
    f16*   Wm1T = (f16*)(ws + (size_t)17 * 1024 * 1024);             // 8 KB
    f16*   Wm2T = (f16*)(ws + (size_t)17 * 1024 * 1024 + 8192);      // 8 KB

    k_proj_s<<<dim3(BB * NN / 2), dim3(256), 0, stream>>>(s, Ws1, bs1, Ws2, bs2, s1t, s2t);
    k_proj_v<<<dim3(BB * NN), dim3(256), 0, stream>>>(v1, v0, Wv1, Wv2, V1t, V2t);
    k_prep_w<<<dim3(1), dim3(256), 0, stream>>>(Wm1, Wm2, Wm1T, Wm2T);
    k_main<<<dim3(BB * (NN / TI) * (NN / TJ)), dim3(512), 0, stream>>>(
        V1t, V2t, s1t, s2t, Wm1T, bm1, Wm2T, bm2, out);
}